// Round 2
// baseline (176.558 us; speedup 1.0000x reference)
//
#include <hip/hip_runtime.h>
#include <stdint.h>

// CriticNetwork: value[b,i,m] = ve[i] + (sv[i] + w[i,m]*dv[m])/64;
// weights5[b,i,m,j] = w[b,i,j]. w = sigmoid(scores/sqrt(128)),
// scores[i,j] = K[i].Q[j] = oa_i (Wk^T Wq) oa_j^T  -> MT trick: no K/Q GEMMs.
// setup: MT[e][d] = sum_c Wk[c,d]Wq[c,e] (bf16), u = Wv^T wf2, g = Wenc^T wf1.
// R11 (= R10 with compile fix): __builtin_nontemporal_store needs a clang
// ext_vector pointer, not HIP float4*. SPLIT the 128 MiB weights5 broadcast:
//   - fused writes w once into the m=0 plane of weights5 (2 MiB) + value (2 MiB)
//   - critic_bcast: 2048 blk x 256 thr, 4 planes/blk, cached 256B row read,
//     nontemporal f32x4 stores (fill-shaped stream) -> tests Model A (internal
//     store-phase limit, expect ~21-30us @ >5TB/s) vs Model B (poison L3->HBM
//     drain bound, expect ~75us @ 1.7TB/s and total ~165us unchanged).
// R9 ledger: every in-block broadcast variant ~80us (1.7 TB/s) vs fill 6.4 TB/s;
// R3 WRITE_SIZE showed poison-drain bleed.

#define BB 128
#define NN 64
#define OBSD 128
#define ACTD 16
#define DD 144
#define DKD 128
#define RS 168   // LDS bf16 row stride: 84 dwords = 20 mod 32 -> conflict-free frags

typedef float f32x4 __attribute__((ext_vector_type(4)));
typedef short bf16x8 __attribute__((ext_vector_type(8)));

// ws: ushort MT[144*160] at 0; float u[144] at F_U; float g[128] at F_G
#define F_U 16384
#define F_G (F_U + 256)

__device__ __forceinline__ unsigned short bf1(float x) {
  unsigned u = __float_as_uint(x);
  return (unsigned short)((u + 0x7fffu + ((u >> 16) & 1u)) >> 16);
}
__device__ __forceinline__ unsigned int pack_bf2(float x, float y) {
  return (unsigned)bf1(x) | ((unsigned)bf1(y) << 16);
}
__device__ __forceinline__ float bf2f(unsigned short s) {
  return __uint_as_float(((unsigned)s) << 16);
}

// ---------------- setup: MT (144 rows) + u + g ----------------
__global__ __launch_bounds__(256) void critic_setup(
    const float* __restrict__ Wk, const float* __restrict__ Wq,
    const float* __restrict__ Wv, const float* __restrict__ Wenc,
    const float* __restrict__ Wfin, float* __restrict__ ws)
{
  const int bid = blockIdx.x, t = threadIdx.x;
  if (bid < DD) {                       // MT row e: MT[e][d] = sum_c Wk[c,d]Wq[c,e]
    const int e = bid;
    if (t < 160) {
      float acc = 0.f;
      if (t < DD) {
        float a0=0.f,a1=0.f,a2=0.f,a3=0.f;
        for (int c = 0; c < DKD; c += 4) {
          a0 += Wk[(c+0)*DD + t] * Wq[(c+0)*DD + e];
          a1 += Wk[(c+1)*DD + t] * Wq[(c+1)*DD + e];
          a2 += Wk[(c+2)*DD + t] * Wq[(c+2)*DD + e];
          a3 += Wk[(c+3)*DD + t] * Wq[(c+3)*DD + e];
        }
        acc = (a0+a1)+(a2+a3);
      }
      ((unsigned short*)ws)[e * 160 + t] = bf1(acc);
    }
  } else if (bid == DD) {               // u[t] = sum_c Wv[c,t] * Wfin[128+c]
    if (t < DD) {
      float a0=0.f,a1=0.f,a2=0.f,a3=0.f;
      for (int c = 0; c < DKD; c += 4) {
        a0 += Wv[(c+0)*DD + t] * Wfin[OBSD + c + 0];
        a1 += Wv[(c+1)*DD + t] * Wfin[OBSD + c + 1];
        a2 += Wv[(c+2)*DD + t] * Wfin[OBSD + c + 2];
        a3 += Wv[(c+3)*DD + t] * Wfin[OBSD + c + 3];
      }
      ws[F_U + t] = (a0+a1)+(a2+a3);
    }
  } else {                              // g[d] = sum_c Wenc[c,d] * Wfin[c]
    if (t < OBSD) {
      float a0=0.f,a1=0.f,a2=0.f,a3=0.f;
      for (int c = 0; c < 128; c += 4) {
        a0 += Wenc[(c+0)*OBSD + t] * Wfin[c + 0];
        a1 += Wenc[(c+1)*OBSD + t] * Wfin[c + 1];
        a2 += Wenc[(c+2)*OBSD + t] * Wfin[c + 2];
        a3 += Wenc[(c+3)*OBSD + t] * Wfin[c + 3];
      }
      ws[F_G + t] = (a0+a1)+(a2+a3);
    }
  }
}

// ---------------- fused: compute value + w (m=0 plane), no broadcast ----------------
// grid 512: bid = b*4 + p; i0 = p*16. 512 threads (8 waves). 72 KB LDS, 2 blk/CU.
__global__ __launch_bounds__(512, 2) void critic_fused(
    const float* __restrict__ obs, const float* __restrict__ pol,
    const float* __restrict__ act, const float* __restrict__ ws,
    float* __restrict__ out)
{
  __shared__ __align__(16) unsigned short s_oa[NN * RS];      // 21504 B
  __shared__ __align__(16) unsigned short s_MT[DD * RS];      // 48384 B; later: s_T + s_w
  __shared__ __align__(16) unsigned short s_dpa[NN * ACTD];   // 2048 B (bf16)
  __shared__ float s_u[DD];
  __shared__ float s_g[OBSD];
  __shared__ float s_vas[NN], s_dv[NN], s_ve[16], s_sv[16];

  unsigned short* s_T = s_MT;                       // 16 rows x RS (alias, after MT dead)
  float* s_w = (float*)(s_MT + 16 * RS);            // [16][68] f32 (alias)

  const int tid = threadIdx.x;
  const int b = blockIdx.x >> 2;
  const int i0 = (blockIdx.x & 3) * 16;

  // ---- stage oa (bf16), dpa (bf16), MT (from ws), u, g
  {
    const float4* obs4 = (const float4*)(obs + (size_t)b * NN * OBSD);
    for (int idx = tid; idx < 2048; idx += 512) {   // 64 rows x 32 f4
      float4 v = obs4[idx];
      int row = idx >> 5, c4 = (idx & 31) * 4;
      *(uint2*)&s_oa[row * RS + c4] = make_uint2(pack_bf2(v.x, v.y), pack_bf2(v.z, v.w));
    }
    if (tid < 256) {                                // act/pol: 64 rows x 4 f4
      const float4* act4 = (const float4*)(act + (size_t)b * NN * ACTD);
      const float4* pol4 = (const float4*)(pol + (size_t)b * NN * ACTD);
      float4 a = act4[tid], pp = pol4[tid];
      int row = tid >> 2, t0 = (tid & 3) * 4;
      *(uint2*)&s_oa[row * RS + OBSD + t0] = make_uint2(pack_bf2(a.x, a.y), pack_bf2(a.z, a.w));
      *(uint2*)&s_dpa[row * ACTD + t0] =
          make_uint2(pack_bf2(pp.x - a.x, pp.y - a.y), pack_bf2(pp.z - a.z, pp.w - a.w));
    } else if (tid < 512) {                         // zero-pad oa cols 144..159
      int idx = tid - 256;                          // 256 = 64 rows x 4 uint2
      int row = idx >> 2, c4 = DD + (idx & 3) * 4;
      *(uint2*)&s_oa[row * RS + c4] = make_uint2(0u, 0u);
    }
    const uint4* mt4 = (const uint4*)ws;            // 144 rows x 20 uint4 (8 bf16)
    for (int idx = tid; idx < 2880; idx += 512) {
      int row = idx / 20, g4 = idx - row * 20;
      *(uint4*)&s_MT[row * RS + g4 * 8] = mt4[idx];
    }
    for (int idx = tid; idx < 288; idx += 512) {    // zero-pad MT cols 144..159
      int row = idx >> 1, h = idx & 1;
      *(uint4*)&s_MT[row * RS + DD + h * 8] = make_uint4(0u, 0u, 0u, 0u);
    }
    if (tid < DD)            s_u[tid] = ws[F_U + tid];
    else if (tid < DD + OBSD) s_g[tid - DD] = ws[F_G + (tid - DD)];
  }
  __syncthreads();

  const int wv = tid >> 6, lane = tid & 63;
  const int m = lane & 15, q = lane >> 4;

  // ---- T = oa[i0..i0+15] x MT^T : 9 e-tiles; wave wv -> tile wv (+ wave0 -> tile 8)
  f32x4 accT = (f32x4){0.f, 0.f, 0.f, 0.f};
  f32x4 accT8 = (f32x4){0.f, 0.f, 0.f, 0.f};
  #pragma unroll
  for (int ks = 0; ks < 5; ++ks) {
    const int koff = ks * 32 + q * 8;
    bf16x8 a = *(const bf16x8*)&s_oa[(i0 + m) * RS + koff];
    bf16x8 bb = *(const bf16x8*)&s_MT[(wv * 16 + m) * RS + koff];
    accT = __builtin_amdgcn_mfma_f32_16x16x32_bf16(a, bb, accT, 0, 0, 0);
    if (wv == 0) {
      bf16x8 b8 = *(const bf16x8*)&s_MT[(128 + m) * RS + koff];
      accT8 = __builtin_amdgcn_mfma_f32_16x16x32_bf16(a, b8, accT8, 0, 0, 0);
    }
  }
  __syncthreads();                                  // all MT reads done -> alias ok

  // ---- write T (bf16) into aliased region; zero-pad T cols 144..159
  #pragma unroll
  for (int r = 0; r < 4; ++r)
    s_T[(q * 4 + r) * RS + wv * 16 + m] = bf1(accT[r]);
  if (wv == 0)
    #pragma unroll
    for (int r = 0; r < 4; ++r)
      s_T[(q * 4 + r) * RS + 128 + m] = bf1(accT8[r]);
  if (tid < 32) {
    int row = tid >> 1, h = tid & 1;
    *(uint4*)&s_T[row * RS + DD + h * 8] = make_uint4(0u, 0u, 0u, 0u);
  }
  __syncthreads();

  // ---- scores (waves 0-3, j-tile = wv) || vas/dv/ve (waves 4-6)
  if (wv < 4) {
    f32x4 sc = (f32x4){0.f, 0.f, 0.f, 0.f};
    #pragma unroll
    for (int ks = 0; ks < 5; ++ks) {
      const int koff = ks * 32 + q * 8;
      bf16x8 a = *(const bf16x8*)&s_T[m * RS + koff];
      bf16x8 bb = *(const bf16x8*)&s_oa[(wv * 16 + m) * RS + koff];
      sc = __builtin_amdgcn_mfma_f32_16x16x32_bf16(a, bb, sc, 0, 0, 0);
    }
    const float kk = 0.08838834764831845f;          // 1/sqrt(128)
    #pragma unroll
    for (int r = 0; r < 4; ++r)
      s_w[(q * 4 + r) * 68 + wv * 16 + m] = 1.0f / (1.0f + __expf(-sc[r] * kk));
  } else if (wv == 4) {                             // dv[m] = dpa[m].u[128:144]
    float a = 0.f;
    #pragma unroll
    for (int t = 0; t < ACTD; ++t) a += bf2f(s_dpa[lane * ACTD + t]) * s_u[OBSD + t];
    s_dv[lane] = a;
  } else if (wv == 5) {                             // vas[j] = oa[j].u
    float a = 0.f;
    for (int d = 0; d < DD; ++d) a += bf2f(s_oa[lane * RS + d]) * s_u[d];
    s_vas[lane] = a;
  } else if (wv == 6 && lane < 16) {                // ve for this block's rows
    float a = 0.f;
    for (int d = 0; d < OBSD; ++d) a += bf2f(s_oa[(i0 + lane) * RS + d]) * s_g[d];
    s_ve[lane] = a;
  }
  __syncthreads();

  if (tid < 16) {                                   // sv[i] = sum_j w[i,j] vas[j]
    float a = 0.f;
    for (int j = 0; j < NN; ++j) a += s_w[tid * 68 + j] * s_vas[j];
    s_sv[tid] = a;
  }
  __syncthreads();

  // ---- value rows [b, i0+r, :]
  if (tid < 256) {
    const int r = tid >> 4, m4 = (tid & 15) * 4;
    float4 v;
    v.x = s_ve[r] + (s_sv[r] + s_w[r * 68 + m4 + 0] * s_dv[m4 + 0]) * (1.0f / 64.0f);
    v.y = s_ve[r] + (s_sv[r] + s_w[r * 68 + m4 + 1] * s_dv[m4 + 1]) * (1.0f / 64.0f);
    v.z = s_ve[r] + (s_sv[r] + s_w[r * 68 + m4 + 2] * s_dv[m4 + 2]) * (1.0f / 64.0f);
    v.w = s_ve[r] + (s_sv[r] + s_w[r * 68 + m4 + 3] * s_dv[m4 + 3]) * (1.0f / 64.0f);
    *(float4*)(out + ((size_t)(b * 64 + i0 + r) * 64 + m4)) = v;
  }

  // ---- w row -> m=0 plane of weights5 (bcast kernel replicates to m=1..63)
  if (tid < 256) {
    const int r = tid >> 4, j4 = (tid & 15) * 4;
    float* w5 = out + (size_t)BB * NN * NN;
    *(float4*)(w5 + (((size_t)(b * 64 + i0 + r)) << 12) + j4) =
        *(const float4*)&s_w[r * 68 + j4];
  }
}

// ---------------- bcast: replicate m=0 row across the 64 m-rows of each plane ----
// 2048 blocks x 256 thr, 4 planes/block. Per plane: each thread loads one f32x4
// of the 256 B w-row (L2/L3 hit) and streams 4 nontemporal f32x4 stores.
// Note: rewriting the m=0 row races with other threads' row loads, but the bits
// stored are the bits loaded from the same location -> benign identical-value race.
__global__ __launch_bounds__(256) void critic_bcast(float* __restrict__ out)
{
  float* w5 = out + (size_t)BB * NN * NN;
  const int tid = threadIdx.x;
  const size_t p0 = (size_t)blockIdx.x * 4;
  #pragma unroll
  for (int qq = 0; qq < 4; ++qq) {
    f32x4* pl = (f32x4*)(w5 + ((p0 + qq) << 12));     // plane: 4096 floats = 1024 f4
    f32x4 v = pl[tid & 15];                           // w-row f32x4 (this thread's lane)
    __builtin_nontemporal_store(v, pl + tid);
    __builtin_nontemporal_store(v, pl + tid + 256);
    __builtin_nontemporal_store(v, pl + tid + 512);
    __builtin_nontemporal_store(v, pl + tid + 768);
  }
}

extern "C" void kernel_launch(void* const* d_in, const int* in_sizes, int n_in,
                              void* d_out, int out_size, void* d_ws, size_t ws_size,
                              hipStream_t stream) {
  (void)in_sizes; (void)n_in; (void)out_size; (void)ws_size;
  const float* obs  = (const float*)d_in[0];
  const float* pol  = (const float*)d_in[1];
  const float* act  = (const float*)d_in[2];
  const float* Wk   = (const float*)d_in[3];
  const float* Wq   = (const float*)d_in[4];
  const float* Wv   = (const float*)d_in[5];
  const float* Wenc = (const float*)d_in[6];
  const float* Wfin = (const float*)d_in[7];
  float* out = (float*)d_out;
  float* ws  = (float*)d_ws;
  hipLaunchKernelGGL(critic_setup, dim3(DD + 2), dim3(256), 0, stream,
                     Wk, Wq, Wv, Wenc, Wfin, ws);
  hipLaunchKernelGGL(critic_fused, dim3(BB * 4), dim3(512), 0, stream,
                     obs, pol, act, ws, out);
  hipLaunchKernelGGL(critic_bcast, dim3(2048), dim3(256), 0, stream, out);
}

// Round 3
// 166.671 us; speedup vs baseline: 1.0593x; 1.0593x over previous
//
#include <hip/hip_runtime.h>
#include <stdint.h>

// CriticNetwork: value[b,i,m] = ve[i] + (sv[i] + w[i,m]*dv[m])/64;
// weights5[b,i,m,j] = w[b,i,j]. w = sigmoid(scores/sqrt(128)),
// scores[i,j] = K[i].Q[j] = oa_i (Wk^T Wq) oa_j^T  -> MT trick: no K/Q GEMMs.
// setup: MT[e][d] = sum_c Wk[c,d]Wq[c,e] (bf16), u = Wv^T wf2, g = Wenc^T wf1.
// R12 ledger (conveyor model): per-iteration HBM write conveyor = 520 MiB poison
// + 130 MiB mandated output at W~2.7 TB/s pure-write => cycle ~241us; fill
// absorbs ~82 visible => our window floor ~159-165us. R0=165.3 (this structure),
// R2 split+NT probe=176.6 (bytes unchanged => conveyor unchanged; NT loses
// write-combining + extra launch). R9: all broadcast variants ~80us "1.7 TB/s"
// = 130 MiB sharing W with ~290 MiB poison backlog drain. Conclusion: time is
// set by write bytes, not kernel structure. This version = R0 revert + issue
// the 128 MiB broadcast stream right after sigmoid (sv/value hide under drain).

#define BB 128
#define NN 64
#define OBSD 128
#define ACTD 16
#define DD 144
#define DKD 128
#define RS 168   // LDS bf16 row stride: 84 dwords = 20 mod 32 -> conflict-free frags

typedef float f32x4 __attribute__((ext_vector_type(4)));
typedef short bf16x8 __attribute__((ext_vector_type(8)));

// ws: ushort MT[144*160] at 0; float u[144] at F_U; float g[128] at F_G
#define F_U 16384
#define F_G (F_U + 256)

__device__ __forceinline__ unsigned short bf1(float x) {
  unsigned u = __float_as_uint(x);
  return (unsigned short)((u + 0x7fffu + ((u >> 16) & 1u)) >> 16);
}
__device__ __forceinline__ unsigned int pack_bf2(float x, float y) {
  return (unsigned)bf1(x) | ((unsigned)bf1(y) << 16);
}
__device__ __forceinline__ float bf2f(unsigned short s) {
  return __uint_as_float(((unsigned)s) << 16);
}

// ---------------- setup: MT (144 rows) + u + g ----------------
__global__ __launch_bounds__(256) void critic_setup(
    const float* __restrict__ Wk, const float* __restrict__ Wq,
    const float* __restrict__ Wv, const float* __restrict__ Wenc,
    const float* __restrict__ Wfin, float* __restrict__ ws)
{
  const int bid = blockIdx.x, t = threadIdx.x;
  if (bid < DD) {                       // MT row e: MT[e][d] = sum_c Wk[c,d]Wq[c,e]
    const int e = bid;
    if (t < 160) {
      float acc = 0.f;
      if (t < DD) {
        float a0=0.f,a1=0.f,a2=0.f,a3=0.f;
        for (int c = 0; c < DKD; c += 4) {
          a0 += Wk[(c+0)*DD + t] * Wq[(c+0)*DD + e];
          a1 += Wk[(c+1)*DD + t] * Wq[(c+1)*DD + e];
          a2 += Wk[(c+2)*DD + t] * Wq[(c+2)*DD + e];
          a3 += Wk[(c+3)*DD + t] * Wq[(c+3)*DD + e];
        }
        acc = (a0+a1)+(a2+a3);
      }
      ((unsigned short*)ws)[e * 160 + t] = bf1(acc);
    }
  } else if (bid == DD) {               // u[t] = sum_c Wv[c,t] * Wfin[128+c]
    if (t < DD) {
      float a0=0.f,a1=0.f,a2=0.f,a3=0.f;
      for (int c = 0; c < DKD; c += 4) {
        a0 += Wv[(c+0)*DD + t] * Wfin[OBSD + c + 0];
        a1 += Wv[(c+1)*DD + t] * Wfin[OBSD + c + 1];
        a2 += Wv[(c+2)*DD + t] * Wfin[OBSD + c + 2];
        a3 += Wv[(c+3)*DD + t] * Wfin[OBSD + c + 3];
      }
      ws[F_U + t] = (a0+a1)+(a2+a3);
    }
  } else {                              // g[d] = sum_c Wenc[c,d] * Wfin[c]
    if (t < OBSD) {
      float a0=0.f,a1=0.f,a2=0.f,a3=0.f;
      for (int c = 0; c < 128; c += 4) {
        a0 += Wenc[(c+0)*OBSD + t] * Wfin[c + 0];
        a1 += Wenc[(c+1)*OBSD + t] * Wfin[c + 1];
        a2 += Wenc[(c+2)*OBSD + t] * Wfin[c + 2];
        a3 += Wenc[(c+3)*OBSD + t] * Wfin[c + 3];
      }
      ws[F_G + t] = (a0+a1)+(a2+a3);
    }
  }
}

// ---------------- fused: everything else, one dispatch ----------------
// grid 512: bid = b*4 + p; i0 = p*16. 512 threads (8 waves). 72 KB LDS, 2 blk/CU.
__global__ __launch_bounds__(512, 2) void critic_fused(
    const float* __restrict__ obs, const float* __restrict__ pol,
    const float* __restrict__ act, const float* __restrict__ ws,
    float* __restrict__ out)
{
  __shared__ __align__(16) unsigned short s_oa[NN * RS];      // 21504 B
  __shared__ __align__(16) unsigned short s_MT[DD * RS];      // 48384 B; later: s_T + s_w
  __shared__ __align__(16) unsigned short s_dpa[NN * ACTD];   // 2048 B (bf16)
  __shared__ float s_u[DD];
  __shared__ float s_g[OBSD];
  __shared__ float s_vas[NN], s_dv[NN], s_ve[16], s_sv[16];

  unsigned short* s_T = s_MT;                       // 16 rows x RS (alias, after MT dead)
  float* s_w = (float*)(s_MT + 16 * RS);            // [16][68] f32 (alias)

  const int tid = threadIdx.x;
  const int b = blockIdx.x >> 2;
  const int i0 = (blockIdx.x & 3) * 16;

  // ---- stage oa (bf16), dpa (bf16), MT (from ws), u, g
  {
    const float4* obs4 = (const float4*)(obs + (size_t)b * NN * OBSD);
    for (int idx = tid; idx < 2048; idx += 512) {   // 64 rows x 32 f4
      float4 v = obs4[idx];
      int row = idx >> 5, c4 = (idx & 31) * 4;
      *(uint2*)&s_oa[row * RS + c4] = make_uint2(pack_bf2(v.x, v.y), pack_bf2(v.z, v.w));
    }
    if (tid < 256) {                                // act/pol: 64 rows x 4 f4
      const float4* act4 = (const float4*)(act + (size_t)b * NN * ACTD);
      const float4* pol4 = (const float4*)(pol + (size_t)b * NN * ACTD);
      float4 a = act4[tid], pp = pol4[tid];
      int row = tid >> 2, t0 = (tid & 3) * 4;
      *(uint2*)&s_oa[row * RS + OBSD + t0] = make_uint2(pack_bf2(a.x, a.y), pack_bf2(a.z, a.w));
      *(uint2*)&s_dpa[row * ACTD + t0] =
          make_uint2(pack_bf2(pp.x - a.x, pp.y - a.y), pack_bf2(pp.z - a.z, pp.w - a.w));
    } else if (tid < 512) {                         // zero-pad oa cols 144..159
      int idx = tid - 256;                          // 256 = 64 rows x 4 uint2
      int row = idx >> 2, c4 = DD + (idx & 3) * 4;
      *(uint2*)&s_oa[row * RS + c4] = make_uint2(0u, 0u);
    }
    const uint4* mt4 = (const uint4*)ws;            // 144 rows x 20 uint4 (8 bf16)
    for (int idx = tid; idx < 2880; idx += 512) {
      int row = idx / 20, g4 = idx - row * 20;
      *(uint4*)&s_MT[row * RS + g4 * 8] = mt4[idx];
    }
    for (int idx = tid; idx < 288; idx += 512) {    // zero-pad MT cols 144..159
      int row = idx >> 1, h = idx & 1;
      *(uint4*)&s_MT[row * RS + DD + h * 8] = make_uint4(0u, 0u, 0u, 0u);
    }
    if (tid < DD)            s_u[tid] = ws[F_U + tid];
    else if (tid < DD + OBSD) s_g[tid - DD] = ws[F_G + (tid - DD)];
  }
  __syncthreads();

  const int wv = tid >> 6, lane = tid & 63;
  const int m = lane & 15, q = lane >> 4;

  // ---- T = oa[i0..i0+15] x MT^T : 9 e-tiles; wave wv -> tile wv (+ wave0 -> tile 8)
  f32x4 accT = (f32x4){0.f, 0.f, 0.f, 0.f};
  f32x4 accT8 = (f32x4){0.f, 0.f, 0.f, 0.f};
  #pragma unroll
  for (int ks = 0; ks < 5; ++ks) {
    const int koff = ks * 32 + q * 8;
    bf16x8 a = *(const bf16x8*)&s_oa[(i0 + m) * RS + koff];
    bf16x8 bb = *(const bf16x8*)&s_MT[(wv * 16 + m) * RS + koff];
    accT = __builtin_amdgcn_mfma_f32_16x16x32_bf16(a, bb, accT, 0, 0, 0);
    if (wv == 0) {
      bf16x8 b8 = *(const bf16x8*)&s_MT[(128 + m) * RS + koff];
      accT8 = __builtin_amdgcn_mfma_f32_16x16x32_bf16(a, b8, accT8, 0, 0, 0);
    }
  }
  __syncthreads();                                  // all MT reads done -> alias ok

  // ---- write T (bf16) into aliased region; zero-pad T cols 144..159
  #pragma unroll
  for (int r = 0; r < 4; ++r)
    s_T[(q * 4 + r) * RS + wv * 16 + m] = bf1(accT[r]);
  if (wv == 0)
    #pragma unroll
    for (int r = 0; r < 4; ++r)
      s_T[(q * 4 + r) * RS + 128 + m] = bf1(accT8[r]);
  if (tid < 32) {
    int row = tid >> 1, h = tid & 1;
    *(uint4*)&s_T[row * RS + DD + h * 8] = make_uint4(0u, 0u, 0u, 0u);
  }
  __syncthreads();

  // ---- scores (waves 0-3, j-tile = wv) || vas/dv/ve (waves 4-6)
  if (wv < 4) {
    f32x4 sc = (f32x4){0.f, 0.f, 0.f, 0.f};
    #pragma unroll
    for (int ks = 0; ks < 5; ++ks) {
      const int koff = ks * 32 + q * 8;
      bf16x8 a = *(const bf16x8*)&s_T[m * RS + koff];
      bf16x8 bb = *(const bf16x8*)&s_oa[(wv * 16 + m) * RS + koff];
      sc = __builtin_amdgcn_mfma_f32_16x16x32_bf16(a, bb, sc, 0, 0, 0);
    }
    const float kk = 0.08838834764831845f;          // 1/sqrt(128)
    #pragma unroll
    for (int r = 0; r < 4; ++r)
      s_w[(q * 4 + r) * 68 + wv * 16 + m] = 1.0f / (1.0f + __expf(-sc[r] * kk));
  } else if (wv == 4) {                             // dv[m] = dpa[m].u[128:144]
    float a = 0.f;
    #pragma unroll
    for (int t = 0; t < ACTD; ++t) a += bf2f(s_dpa[lane * ACTD + t]) * s_u[OBSD + t];
    s_dv[lane] = a;
  } else if (wv == 5) {                             // vas[j] = oa[j].u
    float a = 0.f;
    for (int d = 0; d < DD; ++d) a += bf2f(s_oa[lane * RS + d]) * s_u[d];
    s_vas[lane] = a;
  } else if (wv == 6 && lane < 16) {                // ve for this block's rows
    float a = 0.f;
    for (int d = 0; d < OBSD; ++d) a += bf2f(s_oa[(i0 + lane) * RS + d]) * s_g[d];
    s_ve[lane] = a;
  }
  __syncthreads();

  // ---- broadcast FIRST: 16 planes x 16 KB, coalesced float4 (2/thread/plane).
  // Cached (non-NT) stores: write-hits on still-dirty poison lines elide drain.
  // sv/value phases below hide under the store drain (fire-and-forget issue).
  float* w5 = out + (size_t)BB * NN * NN;
  #pragma unroll 4
  for (int r = 0; r < 16; ++r) {
    const float4 wv4 = *(const float4*)&s_w[r * 68 + (tid & 15) * 4];
    float4* p4 = (float4*)(w5 + ((size_t)(b * 64 + i0 + r) << 12));
    p4[tid]       = wv4;
    p4[tid + 512] = wv4;
  }

  if (tid < 16) {                                   // sv[i] = sum_j w[i,j] vas[j]
    float a = 0.f;
    for (int j = 0; j < NN; ++j) a += s_w[tid * 68 + j] * s_vas[j];
    s_sv[tid] = a;
  }
  __syncthreads();

  // ---- value rows [b, i0+r, :]
  if (tid < 256) {
    const int r = tid >> 4, m4 = (tid & 15) * 4;
    float4 v;
    v.x = s_ve[r] + (s_sv[r] + s_w[r * 68 + m4 + 0] * s_dv[m4 + 0]) * (1.0f / 64.0f);
    v.y = s_ve[r] + (s_sv[r] + s_w[r * 68 + m4 + 1] * s_dv[m4 + 1]) * (1.0f / 64.0f);
    v.z = s_ve[r] + (s_sv[r] + s_w[r * 68 + m4 + 2] * s_dv[m4 + 2]) * (1.0f / 64.0f);
    v.w = s_ve[r] + (s_sv[r] + s_w[r * 68 + m4 + 3] * s_dv[m4 + 3]) * (1.0f / 64.0f);
    *(float4*)(out + ((size_t)(b * 64 + i0 + r) * 64 + m4)) = v;
  }
}

extern "C" void kernel_launch(void* const* d_in, const int* in_sizes, int n_in,
                              void* d_out, int out_size, void* d_ws, size_t ws_size,
                              hipStream_t stream) {
  (void)in_sizes; (void)n_in; (void)out_size; (void)ws_size;
  const float* obs  = (const float*)d_in[0];
  const float* pol  = (const float*)d_in[1];
  const float* act  = (const float*)d_in[2];
  const float* Wk   = (const float*)d_in[3];
  const float* Wq   = (const float*)d_in[4];
  const float* Wv   = (const float*)d_in[5];
  const float* Wenc = (const float*)d_in[6];
  const float* Wfin = (const float*)d_in[7];
  float* out = (float*)d_out;
  float* ws  = (float*)d_ws;
  hipLaunchKernelGGL(critic_setup, dim3(DD + 2), dim3(256), 0, stream,
                     Wk, Wq, Wv, Wenc, Wfin, ws);
  hipLaunchKernelGGL(critic_fused, dim3(BB * 4), dim3(512), 0, stream,
                     obs, pol, act, ws, out);
}